// Round 7
// baseline (141.944 us; speedup 1.0000x reference)
//
#include <hip/hip_runtime.h>
#include <stdint.h>

typedef int   int32x4   __attribute__((ext_vector_type(4)));
typedef int   int32x16  __attribute__((ext_vector_type(16)));
typedef float floatx4   __attribute__((ext_vector_type(4)));

#define B_ROWS 131072
#define DK 512           // K (= D)
#define FN 512           // N (= F)
#define A_SCALE_F ((float)(127.0 / 6.0))

// fused-GEMM geometry: 256 blocks x 1024 threads (16 waves), persistent.
// Wave w owns cols [w*32, w*32+32) x full K; B lives in 64 VGPRs.
#define GBLK 256
#define GT   1024
#define BMS  32
#define GTILES (B_ROWS / BMS / GBLK)   // 16

// ---------------- prepass: quantize weights into B-fragment layout -------------
// 128 blocks x 256 threads; block = 4 cols, 64 row-groups of 8 rows.
__global__ void wq_quant_kernel(const float* __restrict__ kern,  // [DK][FN]
                                int8_t* __restrict__ wq,         // [FN][DK]
                                float* __restrict__ invcs) {     // [FN]
  __shared__ float smax[256];
  __shared__ float sscale[4];
  const int c = threadIdx.x & 3;         // col within block
  const int g = threadIdx.x >> 2;        // row-group 0..63 (8 rows each)
  const int col = blockIdx.x * 4 + c;

  float m = 0.f;
#pragma unroll
  for (int i = 0; i < 8; ++i) {
    m = fmaxf(m, fabsf(kern[(size_t)(g * 8 + i) * FN + col]));
  }
  smax[threadIdx.x] = m;
  __syncthreads();
  if (threadIdx.x < 4) {
    float mm = smax[threadIdx.x];
#pragma unroll 8
    for (int g2 = 1; g2 < 64; ++g2) mm = fmaxf(mm, smax[g2 * 4 + threadIdx.x]);
    const float wb = fmaxf(mm, 1e-6f);
    const float ws = 127.f / wb;               // f32 divide, matches jnp w_scale
    sscale[threadIdx.x] = ws;
    invcs[blockIdx.x * 4 + threadIdx.x] =
        (float)(1.0 / ((double)A_SCALE_F * (double)ws));
  }
  __syncthreads();
  const float ws = sscale[c];
  uint32_t* wq32 = (uint32_t*)(wq + (size_t)col * DK);
#pragma unroll
  for (int d = 0; d < 2; ++d) {                // 8 rows -> 2 packed words
    uint32_t p = 0;
#pragma unroll
    for (int j = 0; j < 4; ++j) {
      float v = kern[(size_t)(g * 8 + d * 4 + j) * FN + col] * ws;
      v = floorf(v + 0.5f);                    // AQT round: floor(v+0.5)
      v = fminf(fmaxf(v, -127.f), 127.f);
      p |= ((uint32_t)((int)v & 255)) << (8 * j);
    }
    wq32[g * 2 + d] = p;
  }
}

// ---------------- fused GEMM: quantize x on the fly, pipelined over 16 tiles ---
// Tile order (T4 discipline — loads must be OLDEST in the vmem queue when the
// quantize consumes them, so the wait is vmcnt(16), never a full drain):
//   1. issue f32 loads(t+1)           [4 x global_load_dwordx4]
//   2. K-loop(t)                      [16 x (ds_read_b128 + MFMA), no vmem]
//   3. epilogue stores(t)             [16 x global_store_dword, newer than loads]
//   4. quantize v[] -> ds_write(t+1)  [compiler waits vmcnt(16): loads only]
//   5. lgkmcnt(0) + s_barrier         [stores float across, drain under next K]
__global__ __launch_bounds__(GT, 4)
void aqt_gemm_fused(const float* __restrict__ x,     // [B_ROWS][DK]
                    const int8_t* __restrict__ wq,   // [FN][DK]
                    const float* __restrict__ invcs, // [FN]
                    const float* __restrict__ bias,  // [FN]
                    float* __restrict__ out) {       // [B_ROWS][FN]
  __shared__ __align__(16) uint8_t xq[2][BMS * DK];  // 2 x 16 KB

  const int tid  = threadIdx.x;
  const int lane = tid & 63;
  const int wv   = tid >> 6;       // 0..15
  const int l31  = lane & 31;
  const int l5   = lane >> 5;

  const int c4 = tid & 127;        // float4 col within a row
  const int r0 = tid >> 7;         // 0..7 -> rows r0, r0+8, r0+16, r0+24

  // ---- B fragments into registers, once (256 KB, L2-hot) ----
  const int col = wv * 32 + l31;
  int32x4 Bf[16];
#pragma unroll
  for (int ks = 0; ks < 16; ++ks)
    Bf[ks] = *(const int32x4*)(wq + (size_t)col * DK + ks * 32 + l5 * 16);
  const float inv = invcs[col];
  const float bv  = bias[col];

  const size_t row0 = (size_t)blockIdx.x * (GTILES * BMS);

  // ---- prologue: stage tile 0 into buffer 0 ----
  {
    const float* xg = x + row0 * DK;
    floatx4 v[4];
#pragma unroll
    for (int i = 0; i < 4; ++i)
      v[i] = *(const floatx4*)(xg + (size_t)(i * 8 + r0) * DK + c4 * 4);
#pragma unroll
    for (int i = 0; i < 4; ++i) {
      const int r = i * 8 + r0;
      uint32_t p = 0;
#pragma unroll
      for (int j = 0; j < 4; ++j) {
        float q = floorf(v[i][j] * A_SCALE_F + 0.5f);   // AQT round
        q = fminf(fmaxf(q, -127.f), 127.f);
        p |= ((uint32_t)((int)q & 255)) << (8 * j);
      }
      *(uint32_t*)(&xq[0][r * DK + ((c4 * 4) ^ ((r & 31) << 4))]) = p;
    }
  }
  asm volatile("s_waitcnt lgkmcnt(0)" ::: "memory");
  __builtin_amdgcn_s_barrier();

  for (int t = 0; t < GTILES; ++t) {
    const uint8_t* bufC = &xq[t & 1][0];
    uint8_t* bufN = &xq[(t & 1) ^ 1][0];
    const size_t rowT = row0 + (size_t)t * BMS;
    const bool pf = (t + 1 < GTILES);

    // ---- (1) issue f32 loads for tile t+1 (oldest vmem ops this tile) ----
    floatx4 v[4];
    if (pf) {
      const float* xg = x + (rowT + BMS) * DK;
#pragma unroll
      for (int i = 0; i < 4; ++i)
        v[i] = *(const floatx4*)(xg + (size_t)(i * 8 + r0) * DK + c4 * 4);
    }
    __builtin_amdgcn_sched_barrier(0);

    // ---- (2) K-loop: LDS A + in-register B only ----
    int32x16 acc = (int32x16)(0);
    const uint8_t* aRow = bufC + l31 * DK;
    const int aswz = l31 << 4;
#pragma unroll
    for (int ks = 0; ks < 16; ++ks) {
      int32x4 a = *(const int32x4*)(aRow + ((ks * 32 + l5 * 16) ^ aswz));
      acc = __builtin_amdgcn_mfma_i32_32x32x32_i8(a, Bf[ks], acc, 0, 0, 0);
    }
    __builtin_amdgcn_sched_barrier(0);

    // ---- (3) epilogue stores (issued AFTER loads -> loads stay oldest) ----
#pragma unroll
    for (int r = 0; r < 16; ++r) {
      const int rowl = (r & 3) + 8 * (r >> 2) + 4 * l5;
      out[(rowT + rowl) * FN + col] = (float)acc[r] * inv + bv;
    }
    __builtin_amdgcn_sched_barrier(0);

    // ---- (4) quantize tile t+1 into the other buffer (vmcnt(16) wait) ----
    if (pf) {
#pragma unroll
      for (int i = 0; i < 4; ++i) {
        const int r = i * 8 + r0;
        uint32_t p = 0;
#pragma unroll
        for (int j = 0; j < 4; ++j) {
          float q = floorf(v[i][j] * A_SCALE_F + 0.5f);   // AQT round
          q = fminf(fmaxf(q, -127.f), 127.f);
          p |= ((uint32_t)((int)q & 255)) << (8 * j);
        }
        *(uint32_t*)(&bufN[r * DK + ((c4 * 4) ^ ((r & 31) << 4))]) = p;
      }
    }

    // ---- (5) ds_writes visible; stores keep draining across the barrier ----
    asm volatile("s_waitcnt lgkmcnt(0)" ::: "memory");
    __builtin_amdgcn_s_barrier();
  }
}

extern "C" void kernel_launch(void* const* d_in, const int* in_sizes, int n_in,
                              void* d_out, int out_size, void* d_ws, size_t ws_size,
                              hipStream_t stream) {
  const float* x    = (const float*)d_in[0];
  const float* kern = (const float*)d_in[1];
  const float* bias = (const float*)d_in[2];
  // d_in[3] = padding_mask: fixed act bounds + eval mode -> not in the math.

  int8_t* wq    = (int8_t*)d_ws;                            // 256 KB
  float*  invcs = (float*)((char*)d_ws + (size_t)FN * DK);  // 2 KB

  wq_quant_kernel<<<128, 256, 0, stream>>>(kern, wq, invcs);
  aqt_gemm_fused<<<GBLK, GT, 0, stream>>>(x, wq, invcs, bias, (float*)d_out);
}